// Round 1
// baseline (307.970 us; speedup 1.0000x reference)
//
#include <hip/hip_runtime.h>
#include <math.h>

#define N_BINS_MAX 1024
#define EPS 1e-4f

__global__ __launch_bounds__(256) void pm_kernel(
    const float* __restrict__ bin_centers, int n_bins,
    const int* __restrict__ idx,
    const float* __restrict__ lb,
    const float* __restrict__ ub,
    float* __restrict__ out,
    long long n_rows)
{
    __shared__ float tab0[N_BINS_MAX];
    __shared__ float tab1[N_BINS_MAX];
    __shared__ float tab2[N_BINS_MAX];

    const float lb0 = lb[0], lb1 = lb[1], lb2 = lb[2];
    const float ub0 = ub[0], ub1 = ub[1], ub2 = ub[2];
    const float r0 = 1.0f / (ub0 - lb0 + EPS);
    const float r1 = 1.0f / (ub1 - lb1 + EPS);
    const float r2 = 1.0f / (ub2 - lb2 + EPS);

    // Build the per-column sigmoid LUTs: 1024 bins x 3 columns = 12 KB LDS.
    // grid is capped at 2048 blocks (8 blocks/CU = 32 waves/CU, the occupancy
    // cap), so this transcendental-heavy build runs 8x less often than the
    // previous 16384-block config (~12.8 us -> ~1.6 us of aggregate VALU).
    for (int i = threadIdx.x; i < n_bins; i += blockDim.x) {
        float c = bin_centers[i];
        float logit = logf(c / (1.0f - c));
        float x0 = (ub0 - logit) * r0;
        float x1 = (ub1 - logit) * r1;
        float x2 = (ub2 - logit) * r2;
        tab0[i] = 1.0f / (1.0f + expf(-x0));
        tab1[i] = 1.0f / (1.0f + expf(-x1));
        tab2[i] = 1.0f / (1.0f + expf(-x2));
    }
    __syncthreads();

    // Hot loop: 4 rows per thread-iteration. Row r uses ints [3r, 3r+2]; a
    // quad of 4 rows is 12 consecutive ints = three aligned int4 loads
    // (48 B/lane, fully consumed across the 3 loads -> 100% line
    // utilization), one float4 store. Grid-stride: ~8 quads per thread.
    const long long n_quads = n_rows >> 2;
    const int4* __restrict__ idx4 = (const int4*)idx;
    float4* __restrict__ out4 = (float4*)out;
    const long long stride = (long long)gridDim.x * blockDim.x;

    #pragma unroll 2
    for (long long q = (long long)blockIdx.x * blockDim.x + threadIdx.x;
         q < n_quads; q += stride) {
        int4 a = idx4[3 * q + 0];
        int4 b = idx4[3 * q + 1];
        int4 c = idx4[3 * q + 2];
        float4 r;
        r.x = tab0[a.x] * tab1[a.y] * tab2[a.z];
        r.y = tab0[a.w] * tab1[b.x] * tab2[b.y];
        r.z = tab0[b.z] * tab1[b.w] * tab2[c.x];
        r.w = tab0[c.y] * tab1[c.z] * tab2[c.w];
        out4[q] = r;
    }

    // Tail rows (n_rows % 4) — none for the bench shape, kept for generality.
    const long long tail_start = n_quads << 2;
    for (long long row = tail_start + (long long)blockIdx.x * blockDim.x + threadIdx.x;
         row < n_rows; row += stride) {
        int i0 = idx[3 * row + 0];
        int i1 = idx[3 * row + 1];
        int i2 = idx[3 * row + 2];
        out[row] = tab0[i0] * tab1[i1] * tab2[i2];
    }
}

extern "C" void kernel_launch(void* const* d_in, const int* in_sizes, int n_in,
                              void* d_out, int out_size, void* d_ws, size_t ws_size,
                              hipStream_t stream) {
    const float* bin_centers = (const float*)d_in[0];
    const int*   idx         = (const int*)d_in[1];
    const float* lb          = (const float*)d_in[2];
    const float* ub          = (const float*)d_in[3];
    // d_in[4] = operator_number (unused by the math)
    float* out = (float*)d_out;

    int n_bins = in_sizes[0];
    long long n_rows = (long long)in_sizes[1] / 3;

    const int block = 256;
    long long n_quads = n_rows >> 2;
    long long want = (n_quads + block - 1) / block;
    if (want < 1) want = 1;
    // 2048 blocks = 8 blocks/CU on 256 CUs = 32 waves/CU (occupancy cap).
    // LDS: 12 KB x 8 = 96 KB < 160 KB, so LDS does not bind occupancy.
    int grid = (int)((want > 2048) ? 2048 : want);

    pm_kernel<<<grid, block, 0, stream>>>(bin_centers, n_bins, idx, lb, ub, out, n_rows);
}

// Round 2
// 304.111 us; speedup vs baseline: 1.0127x; 1.0127x over previous
//
#include <hip/hip_runtime.h>
#include <math.h>

#define N_BINS_MAX 1024
#define EPS 1e-4f
#define BLOCK 512
#define WPB (BLOCK / 64)   // 8 waves per block

__global__ __launch_bounds__(BLOCK) void pm_kernel(
    const float* __restrict__ bin_centers, int n_bins,
    const int* __restrict__ idx,
    const float* __restrict__ lb,
    const float* __restrict__ ub,
    float* __restrict__ out,
    long long n_rows)
{
    __shared__ float tab0[N_BINS_MAX];
    __shared__ float tab1[N_BINS_MAX];
    __shared__ float tab2[N_BINS_MAX];
    // Per-wave SoA staging for the coalesce-then-scatter idx loads:
    // stg[wave][k][d] holds flat int4 F[3d+k] of the wave's 192-int4 chunk.
    __shared__ int4 stg[WPB][3][64];   // 24.5 KB; total LDS 36.9 KB -> 4 blk/CU = 32 waves/CU

    const float lb0 = lb[0], lb1 = lb[1], lb2 = lb[2];
    const float ub0 = ub[0], ub1 = ub[1], ub2 = ub[2];
    const float r0 = 1.0f / (ub0 - lb0 + EPS);
    const float r1 = 1.0f / (ub1 - lb1 + EPS);
    const float r2 = 1.0f / (ub2 - lb2 + EPS);

    // Build the per-column sigmoid LUTs: 1024 bins x 3 columns = 12 KB LDS.
    for (int i = threadIdx.x; i < n_bins; i += blockDim.x) {
        float c = bin_centers[i];
        float logit = logf(c / (1.0f - c));
        float x0 = (ub0 - logit) * r0;
        float x1 = (ub1 - logit) * r1;
        float x2 = (ub2 - logit) * r2;
        tab0[i] = 1.0f / (1.0f + expf(-x0));
        tab1[i] = 1.0f / (1.0f + expf(-x1));
        tab2[i] = 1.0f / (1.0f + expf(-x2));
    }
    __syncthreads();

    const int lane = threadIdx.x & 63;
    const int wid  = threadIdx.x >> 6;

    // Per-lane scatter destinations: load j carries flat int4 f = j*64+lane,
    // which belongs to quad d = f/3, slot k = f%3. Compile-time-unrolled j.
    int d_[3], k_[3];
    #pragma unroll
    for (int j = 0; j < 3; ++j) {
        int f = j * 64 + lane;
        d_[j] = f / 3;            // compiler: magic-mul, hoisted out of loop
        k_[j] = f - 3 * d_[j];
    }

    const long long n_quads = n_rows >> 2;
    const long long nchunk  = n_quads >> 6;          // full 64-quad wave chunks
    const int4* __restrict__ idx4 = (const int4*)idx;
    float4* __restrict__ out4 = (float4*)out;

    // ---- main loop: one 64-quad chunk per wave-iteration ----
    // Loads are perfectly coalesced (64 lanes x contiguous 16 B = 1024 B per
    // instruction, vs the old 48-B-lane-stride pattern that spanned 48 cache
    // lines per instruction). Next chunk's loads are prefetched before the
    // LDS phase so VMEM latency hides under staging+gather+store.
    const long long gws = (long long)gridDim.x * WPB;
    long long ch = (long long)blockIdx.x * WPB + wid;

    if (ch < nchunk) {
        long long f4 = 3 * (ch << 6);
        int4 v0 = idx4[f4 + lane];
        int4 v1 = idx4[f4 + 64 + lane];
        int4 v2 = idx4[f4 + 128 + lane];
        for (;;) {
            const long long cur = ch;
            int4 a0 = v0, a1 = v1, a2 = v2;
            ch += gws;
            if (ch < nchunk) {                 // prefetch next chunk
                long long nf4 = 3 * (ch << 6);
                v0 = idx4[nf4 + lane];
                v1 = idx4[nf4 + 64 + lane];
                v2 = idx4[nf4 + 128 + lane];
            }
            // scatter to per-wave staging (same-wave DS ops are in-order;
            // no barrier needed, waves stay independent)
            stg[wid][k_[0]][d_[0]] = a0;
            stg[wid][k_[1]][d_[1]] = a1;
            stg[wid][k_[2]][d_[2]] = a2;
            asm volatile("" ::: "memory");     // keep compiler from reordering
            int4 a = stg[wid][0][lane];        // = F[3*lane]
            int4 b = stg[wid][1][lane];        // = F[3*lane+1]
            int4 c = stg[wid][2][lane];        // = F[3*lane+2]
            float4 r;
            r.x = tab0[a.x] * tab1[a.y] * tab2[a.z];
            r.y = tab0[a.w] * tab1[b.x] * tab2[b.y];
            r.z = tab0[b.z] * tab1[b.w] * tab2[c.x];
            r.w = tab0[c.y] * tab1[c.z] * tab2[c.w];
            out4[(cur << 6) + lane] = r;       // coalesced 1024 B store
            if (ch >= nchunk) break;
        }
    }

    // ---- leftover quads (n_quads % 64) — old strided per-thread path ----
    const long long done_quads = nchunk << 6;
    const long long tid = (long long)blockIdx.x * BLOCK + threadIdx.x;
    const long long tstride = (long long)gridDim.x * BLOCK;
    for (long long q = done_quads + tid; q < n_quads; q += tstride) {
        int4 a = idx4[3 * q + 0];
        int4 b = idx4[3 * q + 1];
        int4 c = idx4[3 * q + 2];
        float4 r;
        r.x = tab0[a.x] * tab1[a.y] * tab2[a.z];
        r.y = tab0[a.w] * tab1[b.x] * tab2[b.y];
        r.z = tab0[b.z] * tab1[b.w] * tab2[c.x];
        r.w = tab0[c.y] * tab1[c.z] * tab2[c.w];
        out4[q] = r;
    }

    // ---- tail rows (n_rows % 4) — none for the bench shape ----
    const long long tail_start = n_quads << 2;
    for (long long row = tail_start + tid; row < n_rows; row += tstride) {
        int i0 = idx[3 * row + 0];
        int i1 = idx[3 * row + 1];
        int i2 = idx[3 * row + 2];
        out[row] = tab0[i0] * tab1[i1] * tab2[i2];
    }
}

extern "C" void kernel_launch(void* const* d_in, const int* in_sizes, int n_in,
                              void* d_out, int out_size, void* d_ws, size_t ws_size,
                              hipStream_t stream) {
    const float* bin_centers = (const float*)d_in[0];
    const int*   idx         = (const int*)d_in[1];
    const float* lb          = (const float*)d_in[2];
    const float* ub          = (const float*)d_in[3];
    // d_in[4] = operator_number (unused by the math)
    float* out = (float*)d_out;

    int n_bins = in_sizes[0];
    long long n_rows = (long long)in_sizes[1] / 3;

    long long n_quads = n_rows >> 2;
    long long nchunk  = n_quads >> 6;
    long long want = (nchunk + WPB - 1) / WPB;
    if (want < 1) want = 1;
    // 2048 blocks x 8 waves = 16384 waves; 4 blocks/CU resident (LDS-bound
    // at 36.9 KB/block) = 32 waves/CU. Each wave runs ~4 chunks.
    int grid = (int)((want > 2048) ? 2048 : want);

    pm_kernel<<<grid, BLOCK, 0, stream>>>(bin_centers, n_bins, idx, lb, ub, out, n_rows);
}